// Round 4
// baseline (1376.389 us; speedup 1.0000x reference)
//
#include <hip/hip_runtime.h>
#include <stdint.h>
#include <stddef.h>

#define NROWS 32768
#define KCODES 8192
#define DIM 512

#define BM 128
#define BN 128
#define BKC 64
#define KSPLIT 4
#define SEGC (KCODES / KSPLIT) /* 2048 */
#define TAU 1.5e-3f
#define MAXC 64
#define CHAINSPLIT 384 /* OpenBLAS sgemm kc */

typedef __attribute__((ext_vector_type(8))) short short8;
typedef __attribute__((ext_vector_type(4))) float floatx4;
typedef unsigned long long ull;

static __device__ __forceinline__ unsigned short f2bf(float f) {
  unsigned u = __float_as_uint(f);
  unsigned r = (u + 0x7FFFu + ((u >> 16) & 1u)) >> 16;
  return (unsigned short)r;
}
// monotone float->uint key (order-preserving for finite floats)
static __device__ __forceinline__ unsigned fkey(float s) {
  unsigned b = __float_as_uint(s);
  return b ^ (((int)b < 0) ? 0xFFFFFFFFu : 0x80000000u);
}
static __device__ __forceinline__ float keyf(unsigned k) {
  unsigned b = (k & 0x80000000u) ? (k ^ 0x80000000u) : ~k;
  return __uint_as_float(b);
}

#define GLDS16(g, l)                                                        \
  __builtin_amdgcn_global_load_lds(                                         \
      (const __attribute__((address_space(1))) unsigned int*)(g),           \
      (__attribute__((address_space(3))) unsigned int*)(l), 16, 0, 0)

// ---------------------------------------------------------------------------
// numpy-exact row norm: s = x*x (rounded mul), pairwise add.reduce:
// pairwise(512) = (pw(128)+pw(128)) + (pw(128)+pw(128)); pw(128) = 8 strided
// scalar accumulators, tree combine. Then sqrt (RN) and clamp at 1e-12.
// One THREAD per row (chains are inherently sequential). Also zero-inits
// counts / lossacc (ws is poisoned before every call).
// ---------------------------------------------------------------------------
__global__ __launch_bounds__(256) void k_rownorm(const float* __restrict__ x,
                                                 float* __restrict__ nout,
                                                 int nrows,
                                                 int* __restrict__ counts,
                                                 int ninit,
                                                 float* __restrict__ lossacc) {
  const int row = blockIdx.x * 256 + threadIdx.x;
  if (counts != nullptr && row < ninit) counts[row] = 0;
  if (lossacc != nullptr && row == 0) *lossacc = 0.0f;
  if (row >= nrows) return;
  const float* xr = x + (size_t)row * DIM;
  float blk[4];
#pragma unroll
  for (int b = 0; b < 4; ++b) {
    const float* p = xr + b * 128;
    float r[8];
#pragma unroll
    for (int j = 0; j < 8; ++j) r[j] = __fmul_rn(p[j], p[j]);
    for (int i = 8; i < 128; i += 8) {
#pragma unroll
      for (int j = 0; j < 8; ++j)
        r[j] = __fadd_rn(r[j], __fmul_rn(p[i + j], p[i + j]));
    }
    blk[b] = __fadd_rn(__fadd_rn(__fadd_rn(r[0], r[1]), __fadd_rn(r[2], r[3])),
                       __fadd_rn(__fadd_rn(r[4], r[5]), __fadd_rn(r[6], r[7])));
  }
  const float tot =
      __fadd_rn(__fadd_rn(blk[0], blk[1]), __fadd_rn(blk[2], blk[3]));
  nout[row] = fmaxf(__fsqrt_rn(tot), 1e-12f);
}

// ---------------------------------------------------------------------------
// Normalized rows: IEEE divide per element (bit == numpy). Writes bf16 for
// the MFMA filter and optionally the exact fp32 quotient (codebook only).
// One wave per row.
// ---------------------------------------------------------------------------
__global__ __launch_bounds__(256) void k_normstore(const float* __restrict__ x,
                                                   const float* __restrict__ nin,
                                                   unsigned short* __restrict__ xb,
                                                   float* __restrict__ xf) {
  const int wv = threadIdx.x >> 6;
  const int lane = threadIdx.x & 63;
  const int row = blockIdx.x * 4 + wv;
  const float n = nin[row];
  const float4* xr = (const float4*)(x + (size_t)row * DIM);
#pragma unroll
  for (int h = 0; h < 2; ++h) {
    const float4 v = xr[lane + 64 * h];
    const float q0 = __fdiv_rn(v.x, n);
    const float q1 = __fdiv_rn(v.y, n);
    const float q2 = __fdiv_rn(v.z, n);
    const float q3 = __fdiv_rn(v.w, n);
    if (xf != nullptr)
      ((float4*)(xf + (size_t)row * DIM))[lane + 64 * h] =
          make_float4(q0, q1, q2, q3);
    *(ushort4*)(xb + (size_t)row * DIM + 256 * h + 4 * lane) =
        make_ushort4(f2bf(q0), f2bf(q1), f2bf(q2), f2bf(q3));
  }
}

// ---------------------------------------------------------------------------
// bf16 MFMA filter GEMM (noise sigma ~1.7e-4) with per-row running max and
// band-candidate collection (TAU = 1.5e-3 ~= 8.8 sigma).
// Grid: (NROWS/BM, KSPLIT); block 256 (4 waves, 2x2 wave grid, 64x64/wave).
// ---------------------------------------------------------------------------
__global__ __launch_bounds__(256, 2) void k_gemm_collect(
    const unsigned short* __restrict__ znb, const unsigned short* __restrict__ cnb,
    int* __restrict__ counts, int* __restrict__ cands) {
  __shared__ __align__(16) short As[BM * BKC];
  __shared__ __align__(16) short Bs[BN * BKC];
  __shared__ float runmax[BM];
  __shared__ float thresh[BM];
  __shared__ float tmax[BM][2];

  const int tid = threadIdx.x;
  const int lane = tid & 63;
  const int w = tid >> 6;
  const int wm = w >> 1;
  const int wn = w & 1;
  const int row0 = blockIdx.x * BM;
  const int seg0 = blockIdx.y * SEGC;
  const int lrow = lane & 15;
  const int quad = lane >> 4;

  if (tid < BM) runmax[tid] = -2.0f;

  for (int kt = 0; kt < SEGC / BN; ++kt) {
    const int col0 = seg0 + kt * BN;
    floatx4 acc[4][4];
#pragma unroll
    for (int i = 0; i < 4; ++i)
#pragma unroll
      for (int j = 0; j < 4; ++j) {
        floatx4 zz = {0.f, 0.f, 0.f, 0.f};
        acc[i][j] = zz;
      }

    for (int dk = 0; dk < DIM / BKC; ++dk) {
      const int d0 = dk * BKC;
      __syncthreads();
#pragma unroll
      for (int j = 0; j < 4; ++j) {
        const int g = w * 256 + j * 64 + lane;
        const int r = g >> 3;
        const int cs = g & 7;
        const int cg = cs ^ (r & 7);
        GLDS16(znb + (size_t)(row0 + r) * DIM + d0 + cg * 8,
               As + (size_t)(w * 256 + j * 64) * 8);
        GLDS16(cnb + (size_t)(col0 + r) * DIM + d0 + cg * 8,
               Bs + (size_t)(w * 256 + j * 64) * 8);
      }
      __syncthreads();
#pragma unroll
      for (int kk = 0; kk < BKC; kk += 32) {
        short8 af[4], bf[4];
#pragma unroll
        for (int f = 0; f < 4; ++f) {
          const int rA = wm * 64 + f * 16 + lrow;
          const int cA = (kk >> 3) + quad;
          af[f] = *(const short8*)&As[rA * BKC + ((cA ^ (rA & 7)) << 3)];
          const int rB = wn * 64 + f * 16 + lrow;
          bf[f] = *(const short8*)&Bs[rB * BKC + ((cA ^ (rB & 7)) << 3)];
        }
#pragma unroll
        for (int i = 0; i < 4; ++i)
#pragma unroll
          for (int j = 0; j < 4; ++j)
            acc[i][j] = __builtin_amdgcn_mfma_f32_16x16x32_bf16(af[i], bf[j],
                                                                acc[i][j], 0, 0, 0);
      }
    }

    // per-row tile max (C layout: col=lane&15, row=quad*4+reg)
#pragma unroll
    for (int i = 0; i < 4; ++i) {
#pragma unroll
      for (int r = 0; r < 4; ++r) {
        float v = fmaxf(fmaxf(acc[i][0][r], acc[i][1][r]),
                        fmaxf(acc[i][2][r], acc[i][3][r]));
#pragma unroll
        for (int off = 1; off < 16; off <<= 1) v = fmaxf(v, __shfl_xor(v, off, 64));
        if (lrow == 0) tmax[wm * 64 + i * 16 + quad * 4 + r][wn] = v;
      }
    }
    __syncthreads();
    if (tid < BM) {
      const float nm = fmaxf(runmax[tid], fmaxf(tmax[tid][0], tmax[tid][1]));
      runmax[tid] = nm;
      thresh[tid] = nm - TAU;
    }
    __syncthreads();
    // collect candidates within band of running max
#pragma unroll
    for (int i = 0; i < 4; ++i) {
#pragma unroll
      for (int r = 0; r < 4; ++r) {
        const int ml = wm * 64 + i * 16 + quad * 4 + r;
        const float th = thresh[ml];
#pragma unroll
        for (int j = 0; j < 4; ++j) {
          if (acc[i][j][r] >= th) {
            const int rowg = row0 + ml;
            const int slot = atomicAdd(&counts[rowg], 1);
            if (slot < MAXC)
              cands[rowg * MAXC + slot] = col0 + wn * 64 + j * 16 + lrow;
          }
        }
      }
    }
  }
}

// ---------------------------------------------------------------------------
// fp32-EMULATED rescore, reproducing the numpy reference bits:
// score = fp32 fmaf-chain over d ascending split at 384 (sgemm kc blocking),
// inputs = IEEE-divided zn/cn fp32 bits. Ties -> lowest index (np.argmax).
// One wave per row; one lane per candidate. Fullscan fallback on overflow.
// ---------------------------------------------------------------------------
__global__ __launch_bounds__(256) void k_rescore(
    const float* __restrict__ z, const float* __restrict__ normz,
    const float* __restrict__ cnf, const int* __restrict__ counts,
    const int* __restrict__ cands, int* __restrict__ bestk) {
  __shared__ float zn[4][DIM];
  const int wv = threadIdx.x >> 6;
  const int lane = threadIdx.x & 63;
  const int row = blockIdx.x * 4 + wv;
  const float n = normz[row];
  const float* zr = z + (size_t)row * DIM;
#pragma unroll
  for (int j = 0; j < 8; ++j) {
    const int d = lane * 8 + j;
    zn[wv][d] = __fdiv_rn(zr[d], n);
  }
  __syncthreads();
  const int cnt = counts[row];
  const bool fullscan = (cnt <= 0) || (cnt > MAXC);
  ull best = 0ull;
  if (!fullscan) {
    const int idx = (lane < cnt) ? lane : (cnt - 1);
    const int k = cands[row * MAXC + idx] & (KCODES - 1);
    const float* cr = cnf + (size_t)k * DIM;
    float a1 = 0.f, a2 = 0.f;
    for (int d = 0; d < CHAINSPLIT; d += 4) {
      const float4 c = *(const float4*)(cr + d);
      a1 = fmaf(zn[wv][d], c.x, a1);
      a1 = fmaf(zn[wv][d + 1], c.y, a1);
      a1 = fmaf(zn[wv][d + 2], c.z, a1);
      a1 = fmaf(zn[wv][d + 3], c.w, a1);
    }
    for (int d = CHAINSPLIT; d < DIM; d += 4) {
      const float4 c = *(const float4*)(cr + d);
      a2 = fmaf(zn[wv][d], c.x, a2);
      a2 = fmaf(zn[wv][d + 1], c.y, a2);
      a2 = fmaf(zn[wv][d + 2], c.z, a2);
      a2 = fmaf(zn[wv][d + 3], c.w, a2);
    }
    const float s = __fadd_rn(a1, a2);
    if (lane < cnt) best = ((ull)fkey(s) << 32) | (ull)(8191 - k);
  } else {
    for (int base = 0; base < KCODES; base += 64) {
      const int k = base + lane;
      const float* cr = cnf + (size_t)k * DIM;
      float a1 = 0.f, a2 = 0.f;
      for (int d = 0; d < CHAINSPLIT; d += 4) {
        const float4 c = *(const float4*)(cr + d);
        a1 = fmaf(zn[wv][d], c.x, a1);
        a1 = fmaf(zn[wv][d + 1], c.y, a1);
        a1 = fmaf(zn[wv][d + 2], c.z, a1);
        a1 = fmaf(zn[wv][d + 3], c.w, a1);
      }
      for (int d = CHAINSPLIT; d < DIM; d += 4) {
        const float4 c = *(const float4*)(cr + d);
        a2 = fmaf(zn[wv][d], c.x, a2);
        a2 = fmaf(zn[wv][d + 1], c.y, a2);
        a2 = fmaf(zn[wv][d + 2], c.z, a2);
        a2 = fmaf(zn[wv][d + 3], c.w, a2);
      }
      const float s = __fadd_rn(a1, a2);
      const ull q = ((ull)fkey(s) << 32) | (ull)(8191 - k);
      best = (q > best) ? q : best;
    }
  }
#pragma unroll
  for (int off = 1; off < 64; off <<= 1) {
    const ull o = __shfl_xor(best, off, 64);
    best = (o > best) ? o : best;
  }
  if (lane == 0) bestk[row] = 8191 - (int)(best & 0xFFFFFFFFull);
}

// ---------------------------------------------------------------------------
// Output: zq_out = cnf[best] (exact ref cn bits); indices as float; loss.
// ---------------------------------------------------------------------------
__global__ __launch_bounds__(256) void k_output(
    const float* __restrict__ z, const float* __restrict__ normz,
    const float* __restrict__ cnf, const int* __restrict__ bestk,
    float* __restrict__ out, float* __restrict__ lossacc) {
  const int wv = threadIdx.x >> 6;
  const int lane = threadIdx.x & 63;
  const int row = blockIdx.x * 4 + wv;
  const int k = bestk[row];
  const float n = normz[row];
  const float4* cr = (const float4*)(cnf + (size_t)k * DIM);
  const float4* zr = (const float4*)(z + (size_t)row * DIM);
  float ss = 0.0f;
  float4* orow = (float4*)(out + (size_t)row * DIM);
#pragma unroll
  for (int h = 0; h < 2; ++h) {
    const float4 q = cr[lane + 64 * h];
    const float4 zv = zr[lane + 64 * h];
    orow[lane + 64 * h] = q;
    const float d0 = q.x - __fdiv_rn(zv.x, n);
    const float d1 = q.y - __fdiv_rn(zv.y, n);
    const float d2 = q.z - __fdiv_rn(zv.z, n);
    const float d3 = q.w - __fdiv_rn(zv.w, n);
    ss += d0 * d0 + d1 * d1 + d2 * d2 + d3 * d3;
  }
#pragma unroll
  for (int off = 1; off < 64; off <<= 1) ss += __shfl_xor(ss, off, 64);
  if (lane == 0) {
    atomicAdd(lossacc, ss);
    out[(size_t)NROWS * DIM + row] = (float)k;
  }
}

__global__ void k_loss_final(const float* __restrict__ lossacc,
                             float* __restrict__ out) {
  if (threadIdx.x == 0 && blockIdx.x == 0)
    out[(size_t)NROWS * DIM + NROWS] =
        1.5f * (*lossacc) / (float)((size_t)NROWS * DIM);
}

// ---------------------------------------------------------------------------
extern "C" void kernel_launch(void* const* d_in, const int* in_sizes, int n_in,
                              void* d_out, int out_size, void* d_ws, size_t ws_size,
                              hipStream_t stream) {
  const float* z = (const float*)d_in[0];
  const float* cb = (const float*)d_in[1];
  char* ws = (char*)d_ws;
  // workspace layout, ~64.5 MB total
  float* normz = (float*)(ws);                             // 131072
  float* normc = (float*)(ws + 131072);                    // 32768
  int* counts = (int*)(ws + 163840);                       // 131072
  int* bestk = (int*)(ws + 294912);                        // 131072
  float* lossacc = (float*)(ws + 425984);                  // 4 (padded)
  int* cands = (int*)(ws + 458752);                        // 8388608
  unsigned short* znb = (unsigned short*)(ws + 8847360);   // 33554432
  unsigned short* cnb = (unsigned short*)(ws + 42401792);  // 8388608
  float* cnf = (float*)(ws + 50790400);                    // 16777216
  float* out = (float*)d_out;

  k_rownorm<<<dim3(NROWS / 256), dim3(256), 0, stream>>>(z, normz, NROWS, counts,
                                                         NROWS, lossacc);
  k_rownorm<<<dim3(KCODES / 256), dim3(256), 0, stream>>>(cb, normc, KCODES,
                                                          (int*)nullptr, 0,
                                                          (float*)nullptr);
  k_normstore<<<dim3(NROWS / 4), dim3(256), 0, stream>>>(z, normz, znb,
                                                         (float*)nullptr);
  k_normstore<<<dim3(KCODES / 4), dim3(256), 0, stream>>>(cb, normc, cnb, cnf);
  k_gemm_collect<<<dim3(NROWS / BM, KSPLIT), dim3(256), 0, stream>>>(znb, cnb,
                                                                     counts, cands);
  k_rescore<<<dim3(NROWS / 4), dim3(256), 0, stream>>>(z, normz, cnf, counts,
                                                       cands, bestk);
  k_output<<<dim3(NROWS / 4), dim3(256), 0, stream>>>(z, normz, cnf, bestk, out,
                                                      lossacc);
  k_loss_final<<<dim3(1), dim3(64), 0, stream>>>(lossacc, out);
}

// Round 5
// 1257.087 us; speedup vs baseline: 1.0949x; 1.0949x over previous
//
#include <hip/hip_runtime.h>
#include <stdint.h>
#include <stddef.h>

#define NROWS 32768
#define KCODES 8192
#define DIM 512

#define BM 128
#define BN 128
#define BKC 64
#define KSPLIT 4
#define SEGC (KCODES / KSPLIT) /* 2048 */
#define TAU 1.5e-3f
#define MAXC 64
#define CHAINSPLIT 384 /* OpenBLAS sgemm kc */

typedef __attribute__((ext_vector_type(8))) short short8;
typedef __attribute__((ext_vector_type(4))) float floatx4;
typedef unsigned long long ull;

static __device__ __forceinline__ unsigned short f2bf(float f) {
  unsigned u = __float_as_uint(f);
  unsigned r = (u + 0x7FFFu + ((u >> 16) & 1u)) >> 16;
  return (unsigned short)r;
}
// monotone float->uint key (order-preserving for finite floats)
static __device__ __forceinline__ unsigned fkey(float s) {
  unsigned b = __float_as_uint(s);
  return b ^ (((int)b < 0) ? 0xFFFFFFFFu : 0x80000000u);
}

#define GLDS16(g, l)                                                        \
  __builtin_amdgcn_global_load_lds(                                         \
      (const __attribute__((address_space(1))) unsigned int*)(g),           \
      (__attribute__((address_space(3))) unsigned int*)(l), 16, 0, 0)

// ---------------------------------------------------------------------------
// numpy-exact row norm, lane-parallel: 8 lanes per row, lane j owns numpy's
// strided accumulator r[j] (16 sequential __fadd_rn(__fmul_rn) terms per
// 128-block), tree-combined with shfl_xor(1,2,4) exactly matching
// ((r0+r1)+(r2+r3))+((r4+r5)+(r6+r7)); 4 blocks combined pairwise. Bit-equal
// to the validated sequential version (single-add commutativity only).
// Also zero-inits counts / lossacc.
// ---------------------------------------------------------------------------
__global__ __launch_bounds__(256) void k_rownorm(const float* __restrict__ x,
                                                 float* __restrict__ nout,
                                                 int nrows,
                                                 int* __restrict__ counts,
                                                 int ninit,
                                                 float* __restrict__ lossacc) {
  const int tid = threadIdx.x;
  const int j = tid & 7;
  const int row = blockIdx.x * 32 + (tid >> 3);
  if (counts != nullptr && j == 0 && row < ninit) counts[row] = 0;
  if (lossacc != nullptr && blockIdx.x == 0 && tid == 0) *lossacc = 0.0f;
  if (row >= nrows) return;
  const float* xr = x + (size_t)row * DIM;
  float blk[4];
#pragma unroll
  for (int b = 0; b < 4; ++b) {
    const float* p = xr + b * 128;
    float r = __fmul_rn(p[j], p[j]);
    for (int i = 8; i < 128; i += 8) {
      const float t = p[i + j];
      r = __fadd_rn(r, __fmul_rn(t, t));
    }
    // pairwise tree across the 8 lanes (offsets stay inside the 8-lane group)
    r = __fadd_rn(r, __shfl_xor(r, 1, 64));
    r = __fadd_rn(r, __shfl_xor(r, 2, 64));
    r = __fadd_rn(r, __shfl_xor(r, 4, 64));
    blk[b] = r;
  }
  const float tot =
      __fadd_rn(__fadd_rn(blk[0], blk[1]), __fadd_rn(blk[2], blk[3]));
  if (j == 0) nout[row] = fmaxf(__fsqrt_rn(tot), 1e-12f);
}

// ---------------------------------------------------------------------------
// Normalized rows: IEEE divide per element (bit == numpy). Writes bf16 for
// the MFMA filter and optionally the exact fp32 quotient (codebook only).
// One wave per row.
// ---------------------------------------------------------------------------
__global__ __launch_bounds__(256) void k_normstore(const float* __restrict__ x,
                                                   const float* __restrict__ nin,
                                                   unsigned short* __restrict__ xb,
                                                   float* __restrict__ xf) {
  const int wv = threadIdx.x >> 6;
  const int lane = threadIdx.x & 63;
  const int row = blockIdx.x * 4 + wv;
  const float n = nin[row];
  const float4* xr = (const float4*)(x + (size_t)row * DIM);
#pragma unroll
  for (int h = 0; h < 2; ++h) {
    const float4 v = xr[lane + 64 * h];
    const float q0 = __fdiv_rn(v.x, n);
    const float q1 = __fdiv_rn(v.y, n);
    const float q2 = __fdiv_rn(v.z, n);
    const float q3 = __fdiv_rn(v.w, n);
    if (xf != nullptr)
      ((float4*)(xf + (size_t)row * DIM))[lane + 64 * h] =
          make_float4(q0, q1, q2, q3);
    *(ushort4*)(xb + (size_t)row * DIM + 256 * h + 4 * lane) =
        make_ushort4(f2bf(q0), f2bf(q1), f2bf(q2), f2bf(q3));
  }
}

// ---------------------------------------------------------------------------
// bf16 MFMA filter GEMM with in-register per-row running max + band collect.
// Wave grid 4x1: wave w owns rows w*32..w*32+31 and ALL 128 tile columns, so
// the per-row max/threshold/collect is wave-local (shfl over 16 lanes) -- no
// epilogue __syncthreads, no cross-wave LDS. TAU = 1.5e-3 ~= 8.8 sigma of
// bf16 dot noise. Grid: (NROWS/BM, KSPLIT); 4 blocks/CU co-resident.
// ---------------------------------------------------------------------------
__global__ __launch_bounds__(256, 4) void k_gemm_collect(
    const unsigned short* __restrict__ znb, const unsigned short* __restrict__ cnb,
    int* __restrict__ counts, int* __restrict__ cands) {
  __shared__ __align__(16) short As[BM * BKC];
  __shared__ __align__(16) short Bs[BN * BKC];

  const int tid = threadIdx.x;
  const int lane = tid & 63;
  const int w = tid >> 6;  // wave id: owns rows w*32 + [0,32)
  const int row0 = blockIdx.x * BM;
  const int seg0 = blockIdx.y * SEGC;
  const int lrow = lane & 15;
  const int quad = lane >> 4;

  float runmax[2][4];
#pragma unroll
  for (int i = 0; i < 2; ++i)
#pragma unroll
    for (int r = 0; r < 4; ++r) runmax[i][r] = -2.0f;

  for (int kt = 0; kt < SEGC / BN; ++kt) {
    const int col0 = seg0 + kt * BN;
    floatx4 acc[2][8];
#pragma unroll
    for (int i = 0; i < 2; ++i)
#pragma unroll
      for (int j = 0; j < 8; ++j) {
        floatx4 zz = {0.f, 0.f, 0.f, 0.f};
        acc[i][j] = zz;
      }

    for (int dk = 0; dk < DIM / BKC; ++dk) {
      const int d0 = dk * BKC;
      __syncthreads();
#pragma unroll
      for (int j = 0; j < 4; ++j) {
        const int g = w * 256 + j * 64 + lane;  // granule id 0..1023
        const int r = g >> 3;                   // tile-local row
        const int cs = g & 7;                   // stored granule col
        const int cg = cs ^ (r & 7);            // logical granule col
        GLDS16(znb + (size_t)(row0 + r) * DIM + d0 + cg * 8,
               As + (size_t)(w * 256 + j * 64) * 8);
        GLDS16(cnb + (size_t)(col0 + r) * DIM + d0 + cg * 8,
               Bs + (size_t)(w * 256 + j * 64) * 8);
      }
      __syncthreads();
#pragma unroll
      for (int kk = 0; kk < BKC; kk += 32) {
        const int cA = (kk >> 3) + quad;
        short8 af[2];
#pragma unroll
        for (int f = 0; f < 2; ++f) {
          const int rA = w * 32 + f * 16 + lrow;
          af[f] = *(const short8*)&As[rA * BKC + ((cA ^ (rA & 7)) << 3)];
        }
#pragma unroll
        for (int jh = 0; jh < 2; ++jh) {
          short8 bf[4];
#pragma unroll
          for (int g = 0; g < 4; ++g) {
            const int rB = (jh * 4 + g) * 16 + lrow;
            bf[g] = *(const short8*)&Bs[rB * BKC + ((cA ^ (rB & 7)) << 3)];
          }
#pragma unroll
          for (int i = 0; i < 2; ++i)
#pragma unroll
            for (int g = 0; g < 4; ++g)
              acc[i][jh * 4 + g] = __builtin_amdgcn_mfma_f32_16x16x32_bf16(
                  af[i], bf[g], acc[i][jh * 4 + g], 0, 0, 0);
        }
      }
    }

    // ---- in-register epilogue (C layout: col=lane&15, row=quad*4+reg)
#pragma unroll
    for (int i = 0; i < 2; ++i) {
#pragma unroll
      for (int r = 0; r < 4; ++r) {
        float v = acc[i][0][r];
#pragma unroll
        for (int j = 1; j < 8; ++j) v = fmaxf(v, acc[i][j][r]);
#pragma unroll
        for (int off = 1; off < 16; off <<= 1) v = fmaxf(v, __shfl_xor(v, off, 64));
        const float nm = fmaxf(runmax[i][r], v);
        runmax[i][r] = nm;
        const float th = nm - TAU;
        const int rowg = row0 + w * 32 + i * 16 + quad * 4 + r;
#pragma unroll
        for (int j = 0; j < 8; ++j) {
          if (acc[i][j][r] >= th) {
            const int slot = atomicAdd(&counts[rowg], 1);
            if (slot < MAXC)
              cands[rowg * MAXC + slot] = col0 + j * 16 + lrow;
          }
        }
      }
    }
  }
}

// ---------------------------------------------------------------------------
// fp32-EMULATED rescore, reproducing the numpy reference bits:
// score = fp32 fmaf-chain over d ascending split at 384 (sgemm kc blocking),
// inputs = IEEE-divided zn/cn fp32 bits. Ties -> lowest index (np.argmax).
// One wave per row; one lane per candidate. Fullscan fallback on overflow.
// ---------------------------------------------------------------------------
__global__ __launch_bounds__(256) void k_rescore(
    const float* __restrict__ z, const float* __restrict__ normz,
    const float* __restrict__ cnf, const int* __restrict__ counts,
    const int* __restrict__ cands, int* __restrict__ bestk) {
  __shared__ float zn[4][DIM];
  const int wv = threadIdx.x >> 6;
  const int lane = threadIdx.x & 63;
  const int row = blockIdx.x * 4 + wv;
  const float n = normz[row];
  const float* zr = z + (size_t)row * DIM;
#pragma unroll
  for (int j = 0; j < 8; ++j) {
    const int d = lane * 8 + j;
    zn[wv][d] = __fdiv_rn(zr[d], n);
  }
  __syncthreads();
  const int cnt = counts[row];
  const bool fullscan = (cnt <= 0) || (cnt > MAXC);
  ull best = 0ull;
  if (!fullscan) {
    const int idx = (lane < cnt) ? lane : (cnt - 1);
    const int k = cands[row * MAXC + idx] & (KCODES - 1);
    const float* cr = cnf + (size_t)k * DIM;
    float a1 = 0.f, a2 = 0.f;
    for (int d = 0; d < CHAINSPLIT; d += 4) {
      const float4 c = *(const float4*)(cr + d);
      a1 = fmaf(zn[wv][d], c.x, a1);
      a1 = fmaf(zn[wv][d + 1], c.y, a1);
      a1 = fmaf(zn[wv][d + 2], c.z, a1);
      a1 = fmaf(zn[wv][d + 3], c.w, a1);
    }
    for (int d = CHAINSPLIT; d < DIM; d += 4) {
      const float4 c = *(const float4*)(cr + d);
      a2 = fmaf(zn[wv][d], c.x, a2);
      a2 = fmaf(zn[wv][d + 1], c.y, a2);
      a2 = fmaf(zn[wv][d + 2], c.z, a2);
      a2 = fmaf(zn[wv][d + 3], c.w, a2);
    }
    const float s = __fadd_rn(a1, a2);
    if (lane < cnt) best = ((ull)fkey(s) << 32) | (ull)(8191 - k);
  } else {
    for (int base = 0; base < KCODES; base += 64) {
      const int k = base + lane;
      const float* cr = cnf + (size_t)k * DIM;
      float a1 = 0.f, a2 = 0.f;
      for (int d = 0; d < CHAINSPLIT; d += 4) {
        const float4 c = *(const float4*)(cr + d);
        a1 = fmaf(zn[wv][d], c.x, a1);
        a1 = fmaf(zn[wv][d + 1], c.y, a1);
        a1 = fmaf(zn[wv][d + 2], c.z, a1);
        a1 = fmaf(zn[wv][d + 3], c.w, a1);
      }
      for (int d = CHAINSPLIT; d < DIM; d += 4) {
        const float4 c = *(const float4*)(cr + d);
        a2 = fmaf(zn[wv][d], c.x, a2);
        a2 = fmaf(zn[wv][d + 1], c.y, a2);
        a2 = fmaf(zn[wv][d + 2], c.z, a2);
        a2 = fmaf(zn[wv][d + 3], c.w, a2);
      }
      const float s = __fadd_rn(a1, a2);
      const ull q = ((ull)fkey(s) << 32) | (ull)(8191 - k);
      best = (q > best) ? q : best;
    }
  }
#pragma unroll
  for (int off = 1; off < 64; off <<= 1) {
    const ull o = __shfl_xor(best, off, 64);
    best = (o > best) ? o : best;
  }
  if (lane == 0) bestk[row] = 8191 - (int)(best & 0xFFFFFFFFull);
}

// ---------------------------------------------------------------------------
// Output: zq_out = cnf[best] (exact ref cn bits); indices as float; loss.
// ---------------------------------------------------------------------------
__global__ __launch_bounds__(256) void k_output(
    const float* __restrict__ z, const float* __restrict__ normz,
    const float* __restrict__ cnf, const int* __restrict__ bestk,
    float* __restrict__ out, float* __restrict__ lossacc) {
  const int wv = threadIdx.x >> 6;
  const int lane = threadIdx.x & 63;
  const int row = blockIdx.x * 4 + wv;
  const int k = bestk[row];
  const float n = normz[row];
  const float4* cr = (const float4*)(cnf + (size_t)k * DIM);
  const float4* zr = (const float4*)(z + (size_t)row * DIM);
  float ss = 0.0f;
  float4* orow = (float4*)(out + (size_t)row * DIM);
#pragma unroll
  for (int h = 0; h < 2; ++h) {
    const float4 q = cr[lane + 64 * h];
    const float4 zv = zr[lane + 64 * h];
    orow[lane + 64 * h] = q;
    const float d0 = q.x - __fdiv_rn(zv.x, n);
    const float d1 = q.y - __fdiv_rn(zv.y, n);
    const float d2 = q.z - __fdiv_rn(zv.z, n);
    const float d3 = q.w - __fdiv_rn(zv.w, n);
    ss += d0 * d0 + d1 * d1 + d2 * d2 + d3 * d3;
  }
#pragma unroll
  for (int off = 1; off < 64; off <<= 1) ss += __shfl_xor(ss, off, 64);
  if (lane == 0) {
    atomicAdd(lossacc, ss);
    out[(size_t)NROWS * DIM + row] = (float)k;
  }
}

__global__ void k_loss_final(const float* __restrict__ lossacc,
                             float* __restrict__ out) {
  if (threadIdx.x == 0 && blockIdx.x == 0)
    out[(size_t)NROWS * DIM + NROWS] =
        1.5f * (*lossacc) / (float)((size_t)NROWS * DIM);
}

// ---------------------------------------------------------------------------
extern "C" void kernel_launch(void* const* d_in, const int* in_sizes, int n_in,
                              void* d_out, int out_size, void* d_ws, size_t ws_size,
                              hipStream_t stream) {
  const float* z = (const float*)d_in[0];
  const float* cb = (const float*)d_in[1];
  char* ws = (char*)d_ws;
  // workspace layout, ~64.5 MB total
  float* normz = (float*)(ws);                             // 131072
  float* normc = (float*)(ws + 131072);                    // 32768
  int* counts = (int*)(ws + 163840);                       // 131072
  int* bestk = (int*)(ws + 294912);                        // 131072
  float* lossacc = (float*)(ws + 425984);                  // 4 (padded)
  int* cands = (int*)(ws + 458752);                        // 8388608
  unsigned short* znb = (unsigned short*)(ws + 8847360);   // 33554432
  unsigned short* cnb = (unsigned short*)(ws + 42401792);  // 8388608
  float* cnf = (float*)(ws + 50790400);                    // 16777216
  float* out = (float*)d_out;

  k_rownorm<<<dim3(NROWS / 32), dim3(256), 0, stream>>>(z, normz, NROWS, counts,
                                                        NROWS, lossacc);
  k_rownorm<<<dim3(KCODES / 32), dim3(256), 0, stream>>>(cb, normc, KCODES,
                                                         (int*)nullptr, 0,
                                                         (float*)nullptr);
  k_normstore<<<dim3(NROWS / 4), dim3(256), 0, stream>>>(z, normz, znb,
                                                         (float*)nullptr);
  k_normstore<<<dim3(KCODES / 4), dim3(256), 0, stream>>>(cb, normc, cnb, cnf);
  k_gemm_collect<<<dim3(NROWS / BM, KSPLIT), dim3(256), 0, stream>>>(znb, cnb,
                                                                     counts, cands);
  k_rescore<<<dim3(NROWS / 4), dim3(256), 0, stream>>>(z, normz, cnf, counts,
                                                       cands, bestk);
  k_output<<<dim3(NROWS / 4), dim3(256), 0, stream>>>(z, normz, cnf, bestk, out,
                                                      lossacc);
  k_loss_final<<<dim3(1), dim3(64), 0, stream>>>(lossacc, out);
}